// Round 5
// baseline (1263.429 us; speedup 1.0000x reference)
//
#include <hip/hip_runtime.h>
#include <hip/hip_fp16.h>

#define HH 1024
#define WW 1024
#define NB 32
#define PLANE (HH*WW)
#define RR 182         // region rows: gy in [by-27, by+154]  (tile 64W x 128H)
#define CS 136         // LDS row stride in halves (272 B: bank rotation +4/row)
typedef unsigned int u32;
typedef unsigned short u16;

// packed half2 ops via ISA asm: v_pk_min/max_f16 return the non-NaN operand (IEEE),
// so NaN doubles as +inf pad (erode) AND -inf pad (dilate).
static __device__ __forceinline__ u32 pmin(u32 a, u32 b){ u32 d; asm("v_pk_min_f16 %0,%1,%2":"=v"(d):"v"(a),"v"(b)); return d; }
static __device__ __forceinline__ u32 pmax(u32 a, u32 b){ u32 d; asm("v_pk_max_f16 %0,%1,%2":"=v"(d):"v"(a),"v"(b)); return d; }
static __device__ __forceinline__ u32 padd(u32 a, u32 b){ u32 d; asm("v_pk_add_f16 %0,%1,%2":"=v"(d):"v"(a),"v"(b)); return d; }
static __device__ __forceinline__ u32 pmul(u32 a, u32 b){ u32 d; asm("v_pk_mul_f16 %0,%1,%2":"=v"(d):"v"(a),"v"(b)); return d; }
static __device__ __forceinline__ u32 psub(u32 a, u32 b){ u32 d; asm("v_pk_add_f16 %0,%1,%2 neg_lo:[0,1] neg_hi:[0,1]":"=v"(d):"v"(a),"v"(b)); return d; }
static __device__ __forceinline__ float h2f(u32 s){ float f; asm("v_cvt_f32_f16 %0,%1":"=v"(f):"v"(s)); return f; }
static __device__ __forceinline__ u32 cvt2(float a, float b){
    typedef __fp16 h2v __attribute__((ext_vector_type(2)));
    union { h2v h; u32 u; } r; r.h = __builtin_amdgcn_cvt_pkrtz(a,b); return r.u;
}
// DPP: lane i <- lane i-1 / i+1 within 16-lane rows; 16-lane boundaries land on
// region cols 0/127 whose edge pixels are provably never needed (margin 5 cols).
#define DPP_SHR1(x) ((u32)__builtin_amdgcn_mov_dpp((int)(x), 0x111, 0xf, 0xf, true))
#define DPP_SHL1(x) ((u32)__builtin_amdgcn_mov_dpp((int)(x), 0x101, 0xf, 0xf, true))
#define QNAN2 0x7e007e00u
#define AB(hi,lo) (((lo)>>16)|((hi)<<16))

__global__ __launch_bounds__(256,3) void cldice_fused(const float* __restrict__ inputs,
                                                      const float* __restrict__ target,
                                                      double* __restrict__ acc) {
    __shared__ __align__(16) u16 buf[RR*CS];   // 49,504 B -> 3 blocks/CU
    const int tid = threadIdx.x;
    const int bx = blockIdx.x*64, by = blockIdx.y*128;
    const int img = blockIdx.z >> 5, n = blockIdx.z & 31;
    const float* xsrc = (img==0) ? inputs : target;   // skeletonize this
    const float* wsrc = (img==0) ? target : inputs;   // weight for tprec/tsens
    const float* im = xsrc + (size_t)n*PLANE;
    const bool interior = (bx>=64 && bx<=896 && by>=128 && by<=768);
    const int r0 = tid>>4, c = tid&15;       // lane layout: 16 rows x 16 col-groups
    const int gx = bx - 32 + 8*c;            // 8-px groups never straddle image edge
    const bool colok = ((unsigned)gx < (unsigned)WW);
    const int rowoff = r0*CS + c*8;          // halves

    // ---- initial load: fp32 global -> fp16 LDS; out-of-image rows/cols = NaN ----
    #pragma unroll
    for (int g = 0; g < 12; g++) {
        int r = r0 + g*16;
        if (r < RR) {
            int gy = by - 27 + r;
            uint4 v;
            if (interior || (colok && (unsigned)gy < (unsigned)HH)) {
                const float* p = im + (size_t)gy*WW + gx;
                float4 f0 = *(const float4*)p, f1 = *(const float4*)(p+4);
                v.x = cvt2(f0.x,f0.y); v.y = cvt2(f0.z,f0.w);
                v.z = cvt2(f1.x,f1.y); v.w = cvt2(f1.z,f1.w);
            } else {
                v = make_uint4(QNAN2,QNAN2,QNAN2,QNAN2);
            }
            *(uint4*)&buf[rowoff + g*16*CS] = v;
        }
    }
    __syncthreads();

    u32 sk[4][4] = {{0,0,0,0},{0,0,0,0},{0,0,0,0},{0,0,0,0}};   // skel: 4 tile groups/thread
    int bc[4];
    #pragma unroll
    for (int j = 0; j < 4; j++) {
        int ti = tid + j*256;
        bc[j] = (27 + (ti>>3))*CS + (4 + (ti&7))*8;   // tile: rows 27..154, cgroups 4..11
    }

    #pragma unroll 1
    for (int t = 0; t < 26; t++) {
        // ---- Phase A: erode x_t (5-pt cross min) -> st regs; rows [t+1,180-t] ----
        uint4 st[12];
        #pragma unroll
        for (int g = 0; g < 12; g++) {
            int r = r0 + g*16;
            bool act = (r >= t+1) & (r <= 180-t);
            if (act) {
                int base = rowoff + g*16*CS;
                uint4 up = *(const uint4*)&buf[base-CS];
                uint4 md = *(const uint4*)&buf[base];
                uint4 dn = *(const uint4*)&buf[base+CS];
                u32 lfs = DPP_SHR1(md.w);     // left px = neighbor group's px7 (high half)
                u32 rts = DPP_SHL1(md.x);     // right px = neighbor group's px0 (low half)
                u32 vx = pmin(up.x,dn.x), vy = pmin(up.y,dn.y);
                u32 vz = pmin(up.z,dn.z), vw = pmin(up.w,dn.w);
                u32 B1 = AB(md.y,md.x), B2 = AB(md.z,md.y), B3 = AB(md.w,md.z);
                u32 B4 = (md.w>>16)|(rts<<16);
                u32 M0 = (md.x<<16)|(lfs>>16);
                uint4 e;
                e.x = pmin(pmin(vx,md.x), pmin(M0,B1));
                e.y = pmin(pmin(vy,md.y), pmin(B1,B2));
                e.z = pmin(pmin(vz,md.z), pmin(B2,B3));
                e.w = pmin(pmin(vw,md.w), pmin(B3,B4));
                if (!interior) {
                    int gy = by - 27 + r;
                    if (!(colok && (unsigned)gy < (unsigned)HH))
                        e = make_uint4(QNAN2,QNAN2,QNAN2,QNAN2);   // keep OOB = NaN
                }
                st[g] = e;
            }
        }
        // save x_t at this thread's tile groups before overwrite
        uint4 xs[4];
        #pragma unroll
        for (int j = 0; j < 4; j++) xs[j] = *(const uint4*)&buf[bc[j]];
        __syncthreads();
        // ---- Phase B: x_{t+1} -> LDS in place ----
        #pragma unroll
        for (int g = 0; g < 12; g++) {
            int r = r0 + g*16;
            if ((r >= t+1) & (r <= 180-t))
                *(uint4*)&buf[rowoff + g*16*CS] = st[g];
        }
        __syncthreads();
        // ---- Phase C: d = dilate3x3(x_{t+1}) at tile; delta; skel update ----
        #pragma unroll
        for (int j = 0; j < 4; j++) {
            int base = bc[j];
            uint4 up = *(const uint4*)&buf[base-CS];
            uint4 md = *(const uint4*)&buf[base];
            uint4 dn = *(const uint4*)&buf[base+CS];
            uint4 vm;
            vm.x = pmax(pmax(up.x,dn.x),md.x);
            vm.y = pmax(pmax(up.y,dn.y),md.y);
            vm.z = pmax(pmax(up.z,dn.z),md.z);
            vm.w = pmax(pmax(up.w,dn.w),md.w);
            u32 lfm = DPP_SHR1(vm.w);
            u32 rtm = DPP_SHL1(vm.x);
            if ((tid&7)==0) {   // left tile boundary: 3-row vertical max from LDS
                u32 a = buf[base-CS-1], b = buf[base-1], d2 = buf[base+CS-1];
                lfm = pmax(pmax(a,b),d2) << 16;
            }
            if ((tid&7)==7) {   // right boundary
                u32 a = buf[base-CS+8], b = buf[base+8], d2 = buf[base+CS+8];
                rtm = pmax(pmax(a,b),d2) & 0xffffu;
            }
            u32 B1 = AB(vm.y,vm.x), B2 = AB(vm.z,vm.y), B3 = AB(vm.w,vm.z);
            u32 B4 = (vm.w>>16)|(rtm<<16);
            u32 M0 = (vm.x<<16)|(lfm>>16);
            uint4 d;
            d.x = pmax(pmax(M0,B1), vm.x);
            d.y = pmax(pmax(B1,B2), vm.y);
            d.z = pmax(pmax(B2,B3), vm.z);
            d.w = pmax(pmax(B3,B4), vm.w);
            uint4 dl;
            dl.x = pmax(psub(xs[j].x,d.x), 0u);
            dl.y = pmax(psub(xs[j].y,d.y), 0u);
            dl.z = pmax(psub(xs[j].z,d.z), 0u);
            dl.w = pmax(psub(xs[j].w,d.w), 0u);
            sk[j][0] = padd(sk[j][0], pmax(psub(dl.x, pmul(sk[j][0],dl.x)), 0u));
            sk[j][1] = padd(sk[j][1], pmax(psub(dl.y, pmul(sk[j][1],dl.y)), 0u));
            sk[j][2] = padd(sk[j][2], pmax(psub(dl.z, pmul(sk[j][2],dl.z)), 0u));
            sk[j][3] = padd(sk[j][3], pmax(psub(dl.w, pmul(sk[j][3],dl.w)), 0u));
        }
        // next Phase A only reads; writes are behind the A->B barrier
    }

    // ---- fused reduction: s0 = sum(skel*w), s1 = sum(skel) ----
    double s0 = 0.0, s1 = 0.0;
    const float* wim = wsrc + (size_t)n*PLANE;
    #pragma unroll
    for (int j = 0; j < 4; j++) {
        int ti = tid + j*256, ty = ti>>3, cx = ti&7;
        const float* p = wim + (size_t)(by+ty)*WW + bx + 8*cx;
        float4 w0 = *(const float4*)p, w1 = *(const float4*)(p+4);
        float f0 = h2f(sk[j][0]&0xffffu), f1 = h2f(sk[j][0]>>16);
        float f2 = h2f(sk[j][1]&0xffffu), f3 = h2f(sk[j][1]>>16);
        float f4 = h2f(sk[j][2]&0xffffu), f5 = h2f(sk[j][2]>>16);
        float f6 = h2f(sk[j][3]&0xffffu), f7 = h2f(sk[j][3]>>16);
        s0 += (double)(f0*w0.x) + (double)(f1*w0.y) + (double)(f2*w0.z) + (double)(f3*w0.w)
            + (double)(f4*w1.x) + (double)(f5*w1.y) + (double)(f6*w1.z) + (double)(f7*w1.w);
        s1 += (double)f0 + (double)f1 + (double)f2 + (double)f3
            + (double)f4 + (double)f5 + (double)f6 + (double)f7;
    }
    #pragma unroll
    for (int off = 32; off > 0; off >>= 1) {
        s0 += __shfl_down(s0, off, 64);
        s1 += __shfl_down(s1, off, 64);
    }
    __syncthreads();               // buf dead; reuse for block reduction
    double* sh = (double*)buf;
    int lane = tid & 63, wid = tid >> 6;
    if (lane == 0) { sh[wid] = s0; sh[4+wid] = s1; }
    __syncthreads();
    if (tid == 0) {
        atomicAdd(&acc[img*2 + 0], sh[0]+sh[1]+sh[2]+sh[3]);
        atomicAdd(&acc[img*2 + 1], sh[4]+sh[5]+sh[6]+sh[7]);
    }
}

__global__ void final_kernel(const double* __restrict__ acc, float* __restrict__ out) {
    double tprec = (acc[0] + 1e-5) / (acc[1] + 1e-5);
    double tsens = (acc[2] + 1e-5) / (acc[3] + 1e-5);
    out[0] = (float)(1.0 - 2.0 * (tprec * tsens) / (tprec + tsens));
}

extern "C" void kernel_launch(void* const* d_in, const int* in_sizes, int n_in,
                              void* d_out, int out_size, void* d_ws, size_t ws_size,
                              hipStream_t stream) {
    const float* target = (const float*)d_in[0];
    const float* inputs = (const float*)d_in[1];
    float* out = (float*)d_out;
    double* acc = (double*)d_ws;

    (void)hipMemsetAsync(acc, 0, 4*sizeof(double), stream);
    dim3 grid(WW/64, HH/128, NB*2);
    cldice_fused<<<grid, dim3(256), 0, stream>>>(inputs, target, acc);
    final_kernel<<<1, 1, 0, stream>>>(acc, out);
}